// Round 2
// baseline (157.166 us; speedup 1.0000x reference)
//
#include <hip/hip_runtime.h>
#include <hip/hip_bf16.h>
#include <cstdint>
#include <cstddef>

#define NTOT 8192
#define KTOT 256
#define DDIM 64

typedef short short8 __attribute__((ext_vector_type(8)));
typedef float floatx16 __attribute__((ext_vector_type(16)));

// ---- workspace layout (bytes) ----
// G_frag: [k32=8][step=260][lane=64][jj=8] bf16  (B-operand, fragment layout)
static constexpr size_t G_ELEMS   = (size_t)8 * 260 * 64 * 8;   // 1,064,960 bf16
static constexpr size_t OFF_CK    = G_ELEMS * 2;                // 2,129,920
static constexpr size_t OFF_WLS   = OFF_CK + 1024;
static constexpr size_t OFF_BPART = OFF_WLS + 1024;
static constexpr size_t OFF_VAL   = 2134016;                    // [z=2][8192][256] f32 = 16 MB

// f32 -> bf16 with round-to-nearest-even, pure integer (no class types)
__device__ __forceinline__ uint16_t f2bf(float x) {
  uint32_t u = __builtin_bit_cast(uint32_t, x);
  uint32_t r = 0x7fffu + ((u >> 16) & 1u);
  return (uint16_t)((u + r) >> 16);
}

__device__ __forceinline__ uint32_t pk2(float a, float b) {
  return (uint32_t)f2bf(a) | ((uint32_t)f2bf(b) << 16);
}

// A-frag: 8 bf16 = s * (ra.x..ra.w, rb.x..rb.w)
__device__ __forceinline__ short8 mk2(float s, float4 ra, float4 rb) {
  union { uint32_t u[4]; short8 v; } f;
  f.u[0] = pk2(s * ra.x, s * ra.y);
  f.u[1] = pk2(s * ra.z, s * ra.w);
  f.u[2] = pk2(s * rb.x, s * rb.y);
  f.u[3] = pk2(s * rb.z, s * rb.w);
  return f.v;
}

__device__ __forceinline__ short8 mk1(float4 ra, float4 rb) {
  union { uint32_t u[4]; short8 v; } f;
  f.u[0] = pk2(ra.x, ra.y);
  f.u[1] = pk2(ra.z, ra.w);
  f.u[2] = pk2(rb.x, rb.y);
  f.u[3] = pk2(rb.z, rb.w);
  return f.v;
}

// ---------------- P0: wls = log_softmax(weigh) over K=256 ----------------
__global__ void p0_softmax(const float* __restrict__ weigh, float* __restrict__ wls) {
  __shared__ float red[256];
  int t = threadIdx.x;
  float v = weigh[t];
  red[t] = v; __syncthreads();
  for (int o = 128; o > 0; o >>= 1) { if (t < o) red[t] = fmaxf(red[t], red[t + o]); __syncthreads(); }
  float m = red[0]; __syncthreads();
  red[t] = __expf(v - m); __syncthreads();
  for (int o = 128; o > 0; o >>= 1) { if (t < o) red[t] += red[t + o]; __syncthreads(); }
  float lse = m + __logf(red[0]);
  wls[t] = v - lse;
}

// ---------------- P1: per-k prep. One block per k. ----------------
// S_k = W'^T W', W' = (I + strict_lower(tri_k)) * diag(tanh(diag_k))
// G_frag pairs u=i*64+j -> -0.5*S[i][j]; x-part u=4096+i -> (S m)[i]
// ck[k] = sum log|lv| + wls[k] - 0.5 * m^T S m
__global__ void p1_prep(const float* __restrict__ means, const float* __restrict__ diag,
                        const float* __restrict__ tri, const float* __restrict__ wls,
                        uint16_t* __restrict__ Gf, float* __restrict__ ck) {
  int k = blockIdx.x;
  int t = threadIdx.x;
  __shared__ float lv[64], ms[64], red[64];
  __shared__ float Wp[64][64];
  __shared__ float SS[64][64];
  __shared__ float logdet_s;

  if (t < 64) {
    float d = diag[k * 64 + t];
    float l = tanhf(d);
    lv[t] = l;
    ms[t] = means[k * 64 + t];
    red[t] = __logf(fabsf(l));
  }
  __syncthreads();

  // build W'
  for (int e = 0; e < 16; ++e) {
    int idx = e * 256 + t;
    int i = idx >> 6, c = idx & 63;
    float L = (c < i) ? tri[k * 4096 + idx] : 0.f;
    float w = ((c == i) ? 1.f : 0.f) + L;
    Wp[i][c] = w * lv[c];
  }
  __syncthreads();

  if (t == 0) {
    float s = 0.f;
    for (int i = 0; i < 64; ++i) s += red[i];
    logdet_s = s;
  }

  // S = W'^T W' : each thread a 4x4 tile
  int i0 = (t >> 4) * 4, j0 = (t & 15) * 4;
  float acc[4][4];
  #pragma unroll
  for (int a = 0; a < 4; ++a)
    #pragma unroll
    for (int b = 0; b < 4; ++b) acc[a][b] = 0.f;
  for (int r = 0; r < 64; ++r) {
    float4 av = *(const float4*)&Wp[r][i0];
    float4 bv = *(const float4*)&Wp[r][j0];
    float aa[4] = {av.x, av.y, av.z, av.w};
    float bb[4] = {bv.x, bv.y, bv.z, bv.w};
    #pragma unroll
    for (int a = 0; a < 4; ++a)
      #pragma unroll
      for (int b = 0; b < 4; ++b) acc[a][b] = fmaf(aa[a], bb[b], acc[a][b]);
  }

  int k32 = k >> 5, kl = k & 31;
  #pragma unroll
  for (int a = 0; a < 4; ++a) {
    #pragma unroll
    for (int b = 0; b < 4; ++b) {
      int i = i0 + a, j = j0 + b;
      float s = acc[a][b];
      SS[i][j] = s;
      int u = i * 64 + j;
      int st = u >> 4, half = (u >> 3) & 1, je = u & 7;
      size_t gi = ((size_t)(k32 * 260 + st) * 64 + half * 32 + kl) * 8 + je;
      Gf[gi] = f2bf(-0.5f * s);
    }
  }
  __syncthreads();

  if (t < 64) {
    float b = 0.f;
    for (int j = 0; j < 64; ++j) b = fmaf(SS[t][j], ms[j], b);
    int st = 256 + (t >> 4), half = (t >> 3) & 1, je = t & 7;
    Gf[((size_t)(k32 * 260 + st) * 64 + half * 32 + kl) * 8 + je] = f2bf(b);
    red[t] = b * ms[t];
  }
  __syncthreads();
  if (t == 0) {
    float msm = 0.f;
    for (int i = 0; i < 64; ++i) msm += red[i];
    ck[k] = logdet_s + wls[k] - 0.5f * msm;
  }
}

// ---------------- K2: the MFMA GEMM ----------------
// grid (64, 4, 2): x = n-block (128 rows), y = k-block (64 cols), z = u-split
// block = 4 waves; wave (wn,wk): 64 rows x 32 cols, 2 row-tiles of 32 (MFMA 32x32x16)
#define GROUP_BODY(GIDX, BCUR, BNEXT, SNEXT, DOPF)                                   \
  do {                                                                               \
    int i_ = ibase + (GIDX);                                                         \
    float xi0 = xl[r0][i_];                                                          \
    float xi1 = xl[r1][i_];                                                          \
    if (DOPF) {                                                                      \
      _Pragma("unroll")                                                              \
      for (int c = 0; c < 4; ++c) BNEXT[c] = Bp[bofs + (size_t)((SNEXT) + c) * 64];  \
    }                                                                                \
    _Pragma("unroll")                                                                \
    for (int c = 0; c < 4; ++c) {                                                    \
      short8 a0 = mk2(xi0, run0a[c], run0b[c]);                                      \
      short8 a1 = mk2(xi1, run1a[c], run1b[c]);                                      \
      short8 bb = __builtin_bit_cast(short8, BCUR[c]);                               \
      acc0 = __builtin_amdgcn_mfma_f32_32x32x16_bf16(a0, bb, acc0, 0, 0, 0);         \
      acc1 = __builtin_amdgcn_mfma_f32_32x32x16_bf16(a1, bb, acc1, 0, 0, 0);         \
    }                                                                                \
  } while (0)

__launch_bounds__(256, 2)
__global__ void k2_gemm(const float* __restrict__ x, const uint16_t* __restrict__ Gf,
                        float* __restrict__ valp) {
  __shared__ float xl[128][65];
  int t = threadIdx.x;
  int bx = blockIdx.x, by = blockIdx.y, bz = blockIdx.z;
  const float* xblk = x + (size_t)bx * 128 * 64;

  // stage x rows into LDS (for the uniform-index scalar multiplier x[row][i])
  for (int e = 0; e < 8; ++e) {
    int lin = e * 1024 + t * 4;
    float4 v = *(const float4*)(xblk + lin);
    int r = lin >> 6, c = lin & 63;
    xl[r][c] = v.x; xl[r][c + 1] = v.y; xl[r][c + 2] = v.z; xl[r][c + 3] = v.w;
  }
  __syncthreads();

  int wave = t >> 6, l = t & 63;
  int wn = wave >> 1, wk = wave & 1;
  int half = l >> 5, lane31 = l & 31;
  int r0 = wn * 64 + lane31;
  int r1 = r0 + 32;

  // per-lane x runs: row r, chunks c*16 + half*8 .. +7
  float4 run0a[4], run0b[4], run1a[4], run1b[4];
  #pragma unroll
  for (int c = 0; c < 4; ++c) {
    int base = c * 16 + half * 8;
    run0a[c] = *(const float4*)(xblk + (size_t)r0 * 64 + base);
    run0b[c] = *(const float4*)(xblk + (size_t)r0 * 64 + base + 4);
    run1a[c] = *(const float4*)(xblk + (size_t)r1 * 64 + base);
    run1b[c] = *(const float4*)(xblk + (size_t)r1 * 64 + base + 4);
  }

  int k32 = by * 2 + wk;
  const uint4* Bp = (const uint4*)Gf;
  size_t bofs = (size_t)(k32 * 260) * 64 + l;

  floatx16 acc0, acc1;
  #pragma unroll
  for (int i = 0; i < 16; ++i) { acc0[i] = 0.f; acc1[i] = 0.f; }

  int sbase = bz * 128;
  int ibase = sbase >> 2;

  uint4 bufA[4], bufB[4];
  #pragma unroll
  for (int c = 0; c < 4; ++c) bufA[c] = Bp[bofs + (size_t)(sbase + c) * 64];

  for (int g = 0; g < 32; g += 2) {
    GROUP_BODY(g, bufA, bufB, sbase + (g + 1) * 4, true);
    GROUP_BODY(g + 1, bufB, bufA, sbase + (g + 2) * 4, ((g + 2) < 32) || (bz == 1));
  }

  if (bz == 1) {
    // tail: steps 256..259 are the raw-x features
    #pragma unroll
    for (int c = 0; c < 4; ++c) {
      short8 a0 = mk1(run0a[c], run0b[c]);
      short8 a1 = mk1(run1a[c], run1b[c]);
      short8 bb = __builtin_bit_cast(short8, bufA[c]);
      acc0 = __builtin_amdgcn_mfma_f32_32x32x16_bf16(a0, bb, acc0, 0, 0, 0);
      acc1 = __builtin_amdgcn_mfma_f32_32x32x16_bf16(a1, bb, acc1, 0, 0, 0);
    }
  }

  // epilogue: C layout col=lane&31, row=(reg&3)+8*(reg>>2)+4*(lane>>5)
  int nbase = bx * 128 + wn * 64;
  int kcol = by * 64 + wk * 32 + lane31;
  float* out = valp + (size_t)bz * NTOT * KTOT;
  #pragma unroll
  for (int reg = 0; reg < 16; ++reg) {
    int row = (reg & 3) + 8 * (reg >> 2) + 4 * half;
    out[(size_t)(nbase + row) * KTOT + kcol] = acc0[reg];
    out[(size_t)(nbase + 32 + row) * KTOT + kcol] = acc1[reg];
  }
}

// ---------------- K3: logsumexp over K per row + block partial sum ----------------
__global__ void k3_lse(const float* __restrict__ valp, const float* __restrict__ ck,
                       float* __restrict__ bpart) {
  __shared__ float red[256];
  int t = threadIdx.x;
  size_t n = (size_t)blockIdx.x * 256 + t;
  const float4* a  = (const float4*)(valp + n * KTOT);
  const float4* b  = (const float4*)(valp + (size_t)NTOT * KTOT + n * KTOT);
  const float4* c4 = (const float4*)ck;
  float m = -3.0e38f;
  for (int j = 0; j < 64; ++j) {
    float4 va = a[j], vb = b[j], vc = c4[j];
    float v0 = va.x + vb.x + vc.x, v1 = va.y + vb.y + vc.y;
    float v2 = va.z + vb.z + vc.z, v3 = va.w + vb.w + vc.w;
    m = fmaxf(m, fmaxf(fmaxf(v0, v1), fmaxf(v2, v3)));
  }
  float s = 0.f;
  for (int j = 0; j < 64; ++j) {
    float4 va = a[j], vb = b[j], vc = c4[j];
    float v0 = va.x + vb.x + vc.x, v1 = va.y + vb.y + vc.y;
    float v2 = va.z + vb.z + vc.z, v3 = va.w + vb.w + vc.w;
    s += __expf(v0 - m) + __expf(v1 - m) + __expf(v2 - m) + __expf(v3 - m);
  }
  float lse = m + __logf(s);
  red[t] = lse; __syncthreads();
  for (int o = 128; o > 0; o >>= 1) { if (t < o) red[t] += red[t + o]; __syncthreads(); }
  if (t == 0) bpart[blockIdx.x] = red[0];
}

// ---------------- K4: final scalar ----------------
__global__ void k4_final(const float* __restrict__ bpart, float* __restrict__ out) {
  if (threadIdx.x == 0) {
    float s = 0.f;
    for (int i = 0; i < 32; ++i) s += bpart[i];
    // out = mean(-logpdf) = -logC - mean(lse);  -logC = 32*log(2*pi)
    out[0] = 58.8120661251f - s / 8192.0f;
  }
}

extern "C" void kernel_launch(void* const* d_in, const int* in_sizes, int n_in,
                              void* d_out, int out_size, void* d_ws, size_t ws_size,
                              hipStream_t stream) {
  const float* x     = (const float*)d_in[0];
  const float* means = (const float*)d_in[1];
  const float* diag  = (const float*)d_in[2];
  const float* tri   = (const float*)d_in[3];
  const float* weigh = (const float*)d_in[4];

  char* ws = (char*)d_ws;
  uint16_t* Gf  = (uint16_t*)ws;
  float* ck     = (float*)(ws + OFF_CK);
  float* wls    = (float*)(ws + OFF_WLS);
  float* bpart  = (float*)(ws + OFF_BPART);
  float* valp   = (float*)(ws + OFF_VAL);

  p0_softmax<<<dim3(1), dim3(256), 0, stream>>>(weigh, wls);
  p1_prep<<<dim3(256), dim3(256), 0, stream>>>(means, diag, tri, wls, Gf, ck);
  k2_gemm<<<dim3(64, 4, 2), dim3(256), 0, stream>>>(x, Gf, valp);
  k3_lse<<<dim3(32), dim3(256), 0, stream>>>(valp, ck, bpart);
  k4_final<<<dim3(1), dim3(64), 0, stream>>>(bpart, (float*)d_out);
}

// Round 3
// 107.420 us; speedup vs baseline: 1.4631x; 1.4631x over previous
//
#include <hip/hip_runtime.h>
#include <cstdint>
#include <cstddef>

#define NTOT 8192
#define KTOT 256

typedef _Float16 half2v __attribute__((ext_vector_type(2)));
typedef _Float16 half8  __attribute__((ext_vector_type(8)));
typedef float floatx16 __attribute__((ext_vector_type(16)));

// ---- workspace layout (bytes) ----
// G_frag: [k32=8][step=260][lane=64][jj=8] f16  (B-operand, fragment layout)
static constexpr size_t G_ELEMS   = (size_t)8 * 260 * 64 * 8;   // 1,064,960 f16
static constexpr size_t OFF_CK    = G_ELEMS * 2;                // 2,129,920
static constexpr size_t OFF_BPART = OFF_CK + 1024;              // 256 floats
static constexpr size_t OFF_VAL   = 2134016;                    // [z=2][8192][256] f32 = 16 MB

// f32 -> f16 RNE, bit pattern (scalar _Float16 is trivially copyable)
__device__ __forceinline__ uint16_t f2h(float x) {
  _Float16 h = (_Float16)x;
  return __builtin_bit_cast(uint16_t, h);
}

// A-frag: 8 f16 = s2 * rp[0..3]  (4 x v_pk_mul_f16)
__device__ __forceinline__ half8 mkh(half2v s, const half2v* rp) {
  union { half2v p[4]; half8 v; } u;
  u.p[0] = s * rp[0]; u.p[1] = s * rp[1]; u.p[2] = s * rp[2]; u.p[3] = s * rp[3];
  return u.v;
}
__device__ __forceinline__ half8 cph(const half2v* rp) {
  union { half2v p[4]; half8 v; } u;
  u.p[0] = rp[0]; u.p[1] = rp[1]; u.p[2] = rp[2]; u.p[3] = rp[3];
  return u.v;
}

// ---------------- P1: per-k prep (incl. redundant log_softmax). 1 block/k ----
// S_k = W'^T W', W' = (I + strict_lower(tri_k)) * diag(tanh(diag_k))
// Gf pairs u=i*64+j -> f16(-0.5*S[i][j]); x-part u=4096+i -> f16((S m)[i])
// ck[k] = sum log|lv| + logsoftmax(w)[k] - 0.5 * m^T S m
__global__ void p1_prep(const float* __restrict__ means, const float* __restrict__ diag,
                        const float* __restrict__ tri, const float* __restrict__ weigh,
                        uint16_t* __restrict__ Gf, float* __restrict__ ck) {
  int k = blockIdx.x;
  int t = threadIdx.x;
  __shared__ float lv[64], ms[64], red[64], wred[256];
  __shared__ float Wp[64][64];
  __shared__ float SS[64][64];
  __shared__ float logdet_s, lse_s;

  // inline softmax denominator over all 256 weights
  float wv = weigh[t];
  wred[t] = wv; __syncthreads();
  for (int o = 128; o > 0; o >>= 1) { if (t < o) wred[t] = fmaxf(wred[t], wred[t + o]); __syncthreads(); }
  float wm = wred[0]; __syncthreads();
  wred[t] = __expf(wv - wm); __syncthreads();
  for (int o = 128; o > 0; o >>= 1) { if (t < o) wred[t] += wred[t + o]; __syncthreads(); }
  if (t == 0) lse_s = wm + __logf(wred[0]);

  if (t < 64) {
    float d = diag[k * 64 + t];
    float l = tanhf(d);
    lv[t] = l;
    ms[t] = means[k * 64 + t];
    red[t] = __logf(fabsf(l));
  }
  __syncthreads();

  // build W'
  for (int e = 0; e < 16; ++e) {
    int idx = e * 256 + t;
    int i = idx >> 6, c = idx & 63;
    float L = (c < i) ? tri[k * 4096 + idx] : 0.f;
    float w = ((c == i) ? 1.f : 0.f) + L;
    Wp[i][c] = w * lv[c];
  }
  __syncthreads();

  if (t == 0) {
    float s = 0.f;
    for (int i = 0; i < 64; ++i) s += red[i];
    logdet_s = s;
  }

  // S = W'^T W' : each thread a 4x4 tile
  int i0 = (t >> 4) * 4, j0 = (t & 15) * 4;
  float acc[4][4];
  #pragma unroll
  for (int a = 0; a < 4; ++a)
    #pragma unroll
    for (int b = 0; b < 4; ++b) acc[a][b] = 0.f;
  for (int r = 0; r < 64; ++r) {
    float4 av = *(const float4*)&Wp[r][i0];
    float4 bv = *(const float4*)&Wp[r][j0];
    float aa[4] = {av.x, av.y, av.z, av.w};
    float bb[4] = {bv.x, bv.y, bv.z, bv.w};
    #pragma unroll
    for (int a = 0; a < 4; ++a)
      #pragma unroll
      for (int b = 0; b < 4; ++b) acc[a][b] = fmaf(aa[a], bb[b], acc[a][b]);
  }

  int k32 = k >> 5, kl = k & 31;
  #pragma unroll
  for (int a = 0; a < 4; ++a) {
    #pragma unroll
    for (int b = 0; b < 4; ++b) {
      int i = i0 + a, j = j0 + b;
      float s = acc[a][b];
      SS[i][j] = s;
      int u = i * 64 + j;
      int st = u >> 4, half = (u >> 3) & 1, je = u & 7;
      size_t gi = ((size_t)(k32 * 260 + st) * 64 + half * 32 + kl) * 8 + je;
      Gf[gi] = f2h(-0.5f * s);
    }
  }
  __syncthreads();

  if (t < 64) {
    float b = 0.f;
    for (int j = 0; j < 64; ++j) b = fmaf(SS[t][j], ms[j], b);
    int st = 256 + (t >> 4), half = (t >> 3) & 1, je = t & 7;
    Gf[((size_t)(k32 * 260 + st) * 64 + half * 32 + kl) * 8 + je] = f2h(b);
    red[t] = b * ms[t];
  }
  __syncthreads();
  if (t == 0) {
    float msm = 0.f;
    for (int i = 0; i < 64; ++i) msm += red[i];
    ck[k] = logdet_s + (weigh[k] - lse_s) - 0.5f * msm;
  }
}

// ---------------- K2: the MFMA GEMM ----------------
// grid (64, 4, 2): x = n-block (128 rows), y = k-block (64 cols), z = u-split
// block = 4 waves; wave (wn,wk): 64 rows x 32 cols, 2 row-tiles of 32 (MFMA 32x32x16 f16)
#define GROUP_BODY(GIDX, BCUR, BNEXT, SNEXT, DOPF)                                   \
  do {                                                                               \
    int i_ = ibase + (GIDX);                                                         \
    float xf0 = xl[r0][i_];                                                          \
    float xf1 = xl[r1][i_];                                                          \
    half2v xi0; xi0[0] = (_Float16)xf0; xi0[1] = xi0[0];                             \
    half2v xi1; xi1[0] = (_Float16)xf1; xi1[1] = xi1[0];                             \
    if (DOPF) {                                                                      \
      _Pragma("unroll")                                                              \
      for (int c = 0; c < 4; ++c) BNEXT[c] = Bp[bofs + (size_t)((SNEXT) + c) * 64];  \
    }                                                                                \
    _Pragma("unroll")                                                                \
    for (int c = 0; c < 4; ++c) {                                                    \
      half8 a0 = mkh(xi0, runh0[c]);                                                 \
      half8 a1 = mkh(xi1, runh1[c]);                                                 \
      half8 bb = __builtin_bit_cast(half8, BCUR[c]);                                 \
      acc0 = __builtin_amdgcn_mfma_f32_32x32x16_f16(a0, bb, acc0, 0, 0, 0);          \
      acc1 = __builtin_amdgcn_mfma_f32_32x32x16_f16(a1, bb, acc1, 0, 0, 0);          \
    }                                                                                \
  } while (0)

__launch_bounds__(256, 2)
__global__ void k2_gemm(const float* __restrict__ x, const uint16_t* __restrict__ Gf,
                        float* __restrict__ valp) {
  __shared__ float xl[128][65];
  int t = threadIdx.x;
  int bx = blockIdx.x, by = blockIdx.y, bz = blockIdx.z;
  const float* xblk = x + (size_t)bx * 128 * 64;

  // stage x rows into LDS (for the uniform-index scalar multiplier x[row][i])
  for (int e = 0; e < 8; ++e) {
    int lin = e * 1024 + t * 4;
    float4 v = *(const float4*)(xblk + lin);
    int r = lin >> 6, c = lin & 63;
    xl[r][c] = v.x; xl[r][c + 1] = v.y; xl[r][c + 2] = v.z; xl[r][c + 3] = v.w;
  }
  __syncthreads();

  int wave = t >> 6, l = t & 63;
  int wn = wave >> 1, wk = wave & 1;
  int half = l >> 5, lane31 = l & 31;
  int r0 = wn * 64 + lane31;
  int r1 = r0 + 32;

  // per-lane x runs in packed f16: row r, chunks c*16 + half*8 .. +7
  half2v runh0[4][4], runh1[4][4];
  #pragma unroll
  for (int c = 0; c < 4; ++c) {
    int base = c * 16 + half * 8;
    float4 ra = *(const float4*)(xblk + (size_t)r0 * 64 + base);
    float4 rb = *(const float4*)(xblk + (size_t)r0 * 64 + base + 4);
    runh0[c][0][0] = (_Float16)ra.x; runh0[c][0][1] = (_Float16)ra.y;
    runh0[c][1][0] = (_Float16)ra.z; runh0[c][1][1] = (_Float16)ra.w;
    runh0[c][2][0] = (_Float16)rb.x; runh0[c][2][1] = (_Float16)rb.y;
    runh0[c][3][0] = (_Float16)rb.z; runh0[c][3][1] = (_Float16)rb.w;
    float4 rc = *(const float4*)(xblk + (size_t)r1 * 64 + base);
    float4 rd = *(const float4*)(xblk + (size_t)r1 * 64 + base + 4);
    runh1[c][0][0] = (_Float16)rc.x; runh1[c][0][1] = (_Float16)rc.y;
    runh1[c][1][0] = (_Float16)rc.z; runh1[c][1][1] = (_Float16)rc.w;
    runh1[c][2][0] = (_Float16)rd.x; runh1[c][2][1] = (_Float16)rd.y;
    runh1[c][3][0] = (_Float16)rd.z; runh1[c][3][1] = (_Float16)rd.w;
  }

  int k32 = by * 2 + wk;
  const uint4* Bp = (const uint4*)Gf;
  size_t bofs = (size_t)(k32 * 260) * 64 + l;

  floatx16 acc0, acc1;
  #pragma unroll
  for (int i = 0; i < 16; ++i) { acc0[i] = 0.f; acc1[i] = 0.f; }

  int sbase = bz * 128;
  int ibase = sbase >> 2;

  uint4 bufA[4], bufB[4];
  #pragma unroll
  for (int c = 0; c < 4; ++c) bufA[c] = Bp[bofs + (size_t)(sbase + c) * 64];

  for (int g = 0; g < 32; g += 2) {
    GROUP_BODY(g, bufA, bufB, sbase + (g + 1) * 4, true);
    GROUP_BODY(g + 1, bufB, bufA, sbase + (g + 2) * 4, ((g + 2) < 32) || (bz == 1));
  }

  if (bz == 1) {
    // tail: steps 256..259 are the raw-x features
    #pragma unroll
    for (int c = 0; c < 4; ++c) {
      half8 a0 = cph(runh0[c]);
      half8 a1 = cph(runh1[c]);
      half8 bb = __builtin_bit_cast(half8, bufA[c]);
      acc0 = __builtin_amdgcn_mfma_f32_32x32x16_f16(a0, bb, acc0, 0, 0, 0);
      acc1 = __builtin_amdgcn_mfma_f32_32x32x16_f16(a1, bb, acc1, 0, 0, 0);
    }
  }

  // epilogue: C layout col=lane&31, row=(reg&3)+8*(reg>>2)+4*(lane>>5)
  int nbase = bx * 128 + wn * 64;
  int kcol = by * 64 + wk * 32 + lane31;
  float* out = valp + (size_t)bz * NTOT * KTOT;
  #pragma unroll
  for (int reg = 0; reg < 16; ++reg) {
    int row = (reg & 3) + 8 * (reg >> 2) + 4 * half;
    out[(size_t)(nbase + row) * KTOT + kcol] = acc0[reg];
    out[(size_t)(nbase + 32 + row) * KTOT + kcol] = acc1[reg];
  }
}

// ---------------- K3: logsumexp over K per row + block partial sum ----------------
// 256 blocks x 256 threads; each wave does 8 rows, coalesced float4 loads,
// shfl butterfly reductions over the 64 lanes (64 lanes x 4 = 256 cols).
__global__ void k3_lse(const float* __restrict__ valp, const float* __restrict__ ck,
                       float* __restrict__ bpart) {
  __shared__ float red[4];
  int t = threadIdx.x;
  int wave = t >> 6, l = t & 63;
  float4 ckv = ((const float4*)ck)[l];
  const float4* b0 = (const float4*)valp;
  const float4* b1 = (const float4*)(valp + (size_t)NTOT * KTOT);
  float acc = 0.f;
  #pragma unroll
  for (int rr = 0; rr < 8; ++rr) {
    size_t n = (size_t)blockIdx.x * 32 + wave * 8 + rr;
    float4 va = b0[n * 64 + l];
    float4 vb = b1[n * 64 + l];
    float v0 = va.x + vb.x + ckv.x, v1 = va.y + vb.y + ckv.y;
    float v2 = va.z + vb.z + ckv.z, v3 = va.w + vb.w + ckv.w;
    float mx = fmaxf(fmaxf(v0, v1), fmaxf(v2, v3));
    #pragma unroll
    for (int o = 32; o > 0; o >>= 1) mx = fmaxf(mx, __shfl_xor(mx, o));
    float s = __expf(v0 - mx) + __expf(v1 - mx) + __expf(v2 - mx) + __expf(v3 - mx);
    #pragma unroll
    for (int o = 32; o > 0; o >>= 1) s += __shfl_xor(s, o);
    acc += mx + __logf(s);
  }
  if (l == 0) red[wave] = acc;
  __syncthreads();
  if (t == 0) bpart[blockIdx.x] = red[0] + red[1] + red[2] + red[3];
}

// ---------------- K4: final scalar ----------------
__global__ void k4_final(const float* __restrict__ bpart, float* __restrict__ out) {
  __shared__ float red[256];
  int t = threadIdx.x;
  red[t] = bpart[t]; __syncthreads();
  for (int o = 128; o > 0; o >>= 1) { if (t < o) red[t] += red[t + o]; __syncthreads(); }
  if (t == 0) out[0] = 58.8120661251f - red[0] / 8192.0f;
}

extern "C" void kernel_launch(void* const* d_in, const int* in_sizes, int n_in,
                              void* d_out, int out_size, void* d_ws, size_t ws_size,
                              hipStream_t stream) {
  const float* x     = (const float*)d_in[0];
  const float* means = (const float*)d_in[1];
  const float* diag  = (const float*)d_in[2];
  const float* tri   = (const float*)d_in[3];
  const float* weigh = (const float*)d_in[4];

  char* ws = (char*)d_ws;
  uint16_t* Gf  = (uint16_t*)ws;
  float* ck     = (float*)(ws + OFF_CK);
  float* bpart  = (float*)(ws + OFF_BPART);
  float* valp   = (float*)(ws + OFF_VAL);

  p1_prep<<<dim3(256), dim3(256), 0, stream>>>(means, diag, tri, weigh, Gf, ck);
  k2_gemm<<<dim3(64, 4, 2), dim3(256), 0, stream>>>(x, Gf, valp);
  k3_lse<<<dim3(256), dim3(256), 0, stream>>>(valp, ck, bpart);
  k4_final<<<dim3(1), dim3(256), 0, stream>>>(bpart, (float*)d_out);
}

// Round 4
// 97.947 us; speedup vs baseline: 1.6046x; 1.0967x over previous
//
#include <hip/hip_runtime.h>
#include <cstdint>
#include <cstddef>

#define NTOT 8192
#define KTOT 256

typedef _Float16 half2v __attribute__((ext_vector_type(2)));
typedef _Float16 half8  __attribute__((ext_vector_type(8)));
typedef float floatx16 __attribute__((ext_vector_type(16)));

// ---- workspace layout (bytes) ----
// G_frag: [k32=8][step=260][lane=64][jj=8] f16  (B-operand, fragment layout)
static constexpr size_t G_ELEMS   = (size_t)8 * 260 * 64 * 8;   // 1,064,960 f16
static constexpr size_t OFF_CK    = G_ELEMS * 2;                // 2,129,920
static constexpr size_t OFF_BPART = OFF_CK + 1024;
static constexpr size_t OFF_VAL   = 2134016;                    // val2: [8192][4 by][2] f32 = 256 KB

__device__ __forceinline__ uint16_t f2h(float x) {
  _Float16 h = (_Float16)x;
  return __builtin_bit_cast(uint16_t, h);
}

// A-frag: 8 f16 = s2 * rp[0..3]  (4 x v_pk_mul_f16)
__device__ __forceinline__ half8 mkh(half2v s, const half2v* rp) {
  union { half2v p[4]; half8 v; } u;
  u.p[0] = s * rp[0]; u.p[1] = s * rp[1]; u.p[2] = s * rp[2]; u.p[3] = s * rp[3];
  return u.v;
}
__device__ __forceinline__ half8 cph(const half2v* rp) {
  union { half2v p[4]; half8 v; } u;
  u.p[0] = rp[0]; u.p[1] = rp[1]; u.p[2] = rp[2]; u.p[3] = rp[3];
  return u.v;
}

// ---------------- P1: per-k prep (incl. redundant log_softmax). 1 block/k ----
__global__ void p1_prep(const float* __restrict__ means, const float* __restrict__ diag,
                        const float* __restrict__ tri, const float* __restrict__ weigh,
                        uint16_t* __restrict__ Gf, float* __restrict__ ck) {
  int k = blockIdx.x;
  int t = threadIdx.x;
  __shared__ float lv[64], ms[64], bv64[64], wred[256];
  __shared__ float Wp[64][68];   // stride 68: float4-aligned, rotating banks
  __shared__ float SS[64][65];   // stride 65: conflict-free scalar columns
  __shared__ float lse_s;

  // log_softmax denominator over all 256 weights
  float wv = weigh[t];
  wred[t] = wv; __syncthreads();
  for (int o = 128; o > 0; o >>= 1) { if (t < o) wred[t] = fmaxf(wred[t], wred[t + o]); __syncthreads(); }
  float wm = wred[0]; __syncthreads();
  wred[t] = __expf(wv - wm); __syncthreads();
  for (int o = 128; o > 0; o >>= 1) { if (t < o) wred[t] += wred[t + o]; __syncthreads(); }
  if (t == 0) lse_s = wm + __logf(wred[0]);

  float logdet0 = 0.f;   // valid in lane 0 of wave 0 after shuffle
  if (t < 64) {
    float d = diag[k * 64 + t];
    float l = tanhf(d);
    lv[t] = l;
    ms[t] = means[k * 64 + t];
    float ld = __logf(fabsf(l));
    #pragma unroll
    for (int o = 32; o > 0; o >>= 1) ld += __shfl_xor(ld, o);
    logdet0 = ld;
  }
  __syncthreads();

  // build W' = (I + strict_lower(tri)) * diag(lv)
  for (int e = 0; e < 16; ++e) {
    int idx = e * 256 + t;
    int i = idx >> 6, c = idx & 63;
    float L = (c < i) ? tri[k * 4096 + idx] : 0.f;
    float w = ((c == i) ? 1.f : 0.f) + L;
    Wp[i][c] = w * lv[c];
  }
  __syncthreads();

  // S = W'^T W' : each thread a 4x4 tile
  int i0 = (t >> 4) * 4, j0 = (t & 15) * 4;
  float acc[4][4];
  #pragma unroll
  for (int a = 0; a < 4; ++a)
    #pragma unroll
    for (int b = 0; b < 4; ++b) acc[a][b] = 0.f;
  for (int r = 0; r < 64; ++r) {
    float4 av = *(const float4*)&Wp[r][i0];
    float4 bv = *(const float4*)&Wp[r][j0];
    float aa[4] = {av.x, av.y, av.z, av.w};
    float bb[4] = {bv.x, bv.y, bv.z, bv.w};
    #pragma unroll
    for (int a = 0; a < 4; ++a)
      #pragma unroll
      for (int b = 0; b < 4; ++b) acc[a][b] = fmaf(aa[a], bb[b], acc[a][b]);
  }
  #pragma unroll
  for (int a = 0; a < 4; ++a)
    #pragma unroll
    for (int b = 0; b < 4; ++b) SS[i0 + a][j0 + b] = acc[a][b];
  __syncthreads();

  // bv = S m  (conflict-free: SS stride 65), msm via shuffle
  if (t < 64) {
    float b = 0.f;
    for (int j = 0; j < 64; ++j) b = fmaf(SS[t][j], ms[j], b);
    bv64[t] = b;
    float bm = b * ms[t];
    #pragma unroll
    for (int o = 32; o > 0; o >>= 1) bm += __shfl_xor(bm, o);
    if (t == 0) ck[k] = logdet0 + (weigh[k] - lse_s) - 0.5f * bm;
  }
  __syncthreads();

  // Gf stores: 520 x 16B chunks. chunk cc covers features u = 8cc..8cc+7.
  // st = cc>>1, half = cc&1 (uniform incl. the Sm tail at cc>=512).
  int k32 = k >> 5, kl = k & 31;
  for (int cc = t; cc < 520; cc += 256) {
    float v[8];
    if (cc < 512) {
      int i = cc >> 3, jb = (cc & 7) * 8;
      #pragma unroll
      for (int e = 0; e < 8; ++e) v[e] = -0.5f * SS[i][jb + e];
    } else {
      int b0 = (cc - 512) * 8;
      #pragma unroll
      for (int e = 0; e < 8; ++e) v[e] = bv64[b0 + e];
    }
    uint4 pk;
    pk.x = (uint32_t)f2h(v[0]) | ((uint32_t)f2h(v[1]) << 16);
    pk.y = (uint32_t)f2h(v[2]) | ((uint32_t)f2h(v[3]) << 16);
    pk.z = (uint32_t)f2h(v[4]) | ((uint32_t)f2h(v[5]) << 16);
    pk.w = (uint32_t)f2h(v[6]) | ((uint32_t)f2h(v[7]) << 16);
    size_t base = ((size_t)(k32 * 260 + (cc >> 1)) * 64 + (cc & 1) * 32 + kl) * 8;
    *(uint4*)(Gf + base) = pk;
  }
}

// ---------------- K2: MFMA GEMM, full-K per block, fused partial-LSE ----------
// grid (64, 4): bx = 128-row block, by = 64-col block. 4 waves:
// wave (wn,wk) = 64 rows x 32 cols, 2 row-tiles of 32 (MFMA 32x32x16 f16).
// Full k-dim: 260 steps (64 groups of 4 + Sm tail). 4-deep B prefetch.
// Epilogue: val2[n][by] = (m, sumexp) over this block's 64 cols (ck included).
__launch_bounds__(256)
__global__ void k2_gemm(const float* __restrict__ x, const uint16_t* __restrict__ Gf,
                        const float* __restrict__ ck, float* __restrict__ val2) {
  __shared__ float xl[128][65];
  int t = threadIdx.x;
  int bx = blockIdx.x, by = blockIdx.y;
  const float* xblk = x + (size_t)bx * (128 * 64);

  for (int e = 0; e < 8; ++e) {
    int lin = e * 1024 + t * 4;
    float4 v = *(const float4*)(xblk + lin);
    int r = lin >> 6, c = lin & 63;
    xl[r][c] = v.x; xl[r][c + 1] = v.y; xl[r][c + 2] = v.z; xl[r][c + 3] = v.w;
  }
  __syncthreads();

  int wave = t >> 6, l = t & 63;
  int wn = wave >> 1, wk = wave & 1;
  int half = l >> 5, lane31 = l & 31;
  int r0 = wn * 64 + lane31, r1 = r0 + 32;

  // per-lane x runs in packed f16: row r, chunks c*16 + half*8 .. +7
  half2v runh0[4][4], runh1[4][4];
  #pragma unroll
  for (int c = 0; c < 4; ++c) {
    int base = c * 16 + half * 8;
    float4 ra = *(const float4*)(xblk + (size_t)r0 * 64 + base);
    float4 rb = *(const float4*)(xblk + (size_t)r0 * 64 + base + 4);
    runh0[c][0][0] = (_Float16)ra.x; runh0[c][0][1] = (_Float16)ra.y;
    runh0[c][1][0] = (_Float16)ra.z; runh0[c][1][1] = (_Float16)ra.w;
    runh0[c][2][0] = (_Float16)rb.x; runh0[c][2][1] = (_Float16)rb.y;
    runh0[c][3][0] = (_Float16)rb.z; runh0[c][3][1] = (_Float16)rb.w;
    float4 rc = *(const float4*)(xblk + (size_t)r1 * 64 + base);
    float4 rd = *(const float4*)(xblk + (size_t)r1 * 64 + base + 4);
    runh1[c][0][0] = (_Float16)rc.x; runh1[c][0][1] = (_Float16)rc.y;
    runh1[c][1][0] = (_Float16)rc.z; runh1[c][1][1] = (_Float16)rc.w;
    runh1[c][2][0] = (_Float16)rd.x; runh1[c][2][1] = (_Float16)rd.y;
    runh1[c][3][0] = (_Float16)rd.z; runh1[c][3][1] = (_Float16)rd.w;
  }

  int k32 = by * 2 + wk;
  const uint4* Bp = (const uint4*)Gf;
  size_t bofs = (size_t)(k32 * 260) * 64 + l;

  floatx16 acc0, acc1;
  #pragma unroll
  for (int i = 0; i < 16; ++i) { acc0[i] = 0.f; acc1[i] = 0.f; }

  // 4-deep prefetch (lead ~4 groups > L2 latency). Overruns past step 259
  // stay inside d_ws (harmless, never consumed).
  uint4 bufs[4][4];
  #pragma unroll
  for (int p = 0; p < 4; ++p)
    #pragma unroll
    for (int c = 0; c < 4; ++c) bufs[p][c] = Bp[bofs + (size_t)(p * 4 + c) * 64];

  for (int g = 0; g < 64; g += 4) {
    #pragma unroll
    for (int p = 0; p < 4; ++p) {
      int gg = g + p;
      float xf0 = xl[r0][gg], xf1 = xl[r1][gg];
      _Float16 h0 = (_Float16)xf0; half2v xi0; xi0[0] = h0; xi0[1] = h0;
      _Float16 h1 = (_Float16)xf1; half2v xi1; xi1[0] = h1; xi1[1] = h1;
      #pragma unroll
      for (int c = 0; c < 4; ++c) {
        half8 a0 = mkh(xi0, runh0[c]);
        half8 a1 = mkh(xi1, runh1[c]);
        half8 bb = __builtin_bit_cast(half8, bufs[p][c]);
        acc0 = __builtin_amdgcn_mfma_f32_32x32x16_f16(a0, bb, acc0, 0, 0, 0);
        acc1 = __builtin_amdgcn_mfma_f32_32x32x16_f16(a1, bb, acc1, 0, 0, 0);
      }
      #pragma unroll
      for (int c = 0; c < 4; ++c)
        bufs[p][c] = Bp[bofs + (size_t)((gg + 4) * 4 + c) * 64];
    }
  }

  // tail: steps 256..259 (Sm features, A = raw x) — prefetched into bufs[0]
  #pragma unroll
  for (int c = 0; c < 4; ++c) {
    half8 a0 = cph(runh0[c]);
    half8 a1 = cph(runh1[c]);
    half8 bb = __builtin_bit_cast(half8, bufs[0][c]);
    acc0 = __builtin_amdgcn_mfma_f32_32x32x16_f16(a0, bb, acc0, 0, 0, 0);
    acc1 = __builtin_amdgcn_mfma_f32_32x32x16_f16(a1, bb, acc1, 0, 0, 0);
  }

  // epilogue: stash val (+ck) into xl (reuse), then per-row partial LSE
  __syncthreads();
  float ckv = ck[by * 64 + wk * 32 + lane31];
  #pragma unroll
  for (int reg = 0; reg < 16; ++reg) {
    int row = (reg & 3) + 8 * (reg >> 2) + 4 * half;
    xl[wn * 64 + row][wk * 32 + lane31] = acc0[reg] + ckv;
    xl[wn * 64 + 32 + row][wk * 32 + lane31] = acc1[reg] + ckv;
  }
  __syncthreads();
  if (t < 128) {
    float m = -3.0e38f;
    #pragma unroll
    for (int j = 0; j < 64; ++j) m = fmaxf(m, xl[t][j]);
    float s = 0.f;
    #pragma unroll
    for (int j = 0; j < 64; ++j) s += __expf(xl[t][j] - m);
    size_t n = (size_t)bx * 128 + t;
    val2[n * 8 + by * 2 + 0] = m;
    val2[n * 8 + by * 2 + 1] = s;
  }
}

// ---------------- K3: combine 4 (m,s) pairs per row -> lse, block sum -------
__global__ void k3_lse(const float* __restrict__ val2, float* __restrict__ bpart) {
  __shared__ float red[4];
  int t = threadIdx.x;
  size_t n = (size_t)blockIdx.x * 256 + t;
  const float4* p = (const float4*)(val2 + n * 8);
  float4 a = p[0], b = p[1];
  float M = fmaxf(fmaxf(a.x, a.z), fmaxf(b.x, b.z));
  float s = a.y * __expf(a.x - M) + a.w * __expf(a.z - M) +
            b.y * __expf(b.x - M) + b.w * __expf(b.z - M);
  float lse = M + __logf(s);
  #pragma unroll
  for (int o = 32; o > 0; o >>= 1) lse += __shfl_xor(lse, o);
  if ((t & 63) == 0) red[t >> 6] = lse;
  __syncthreads();
  if (t == 0) bpart[blockIdx.x] = red[0] + red[1] + red[2] + red[3];
}

// ---------------- K4: final scalar ----------------
__global__ void k4_final(const float* __restrict__ bpart, float* __restrict__ out) {
  int t = threadIdx.x;
  float v = (t < 32) ? bpart[t] : 0.f;
  #pragma unroll
  for (int o = 32; o > 0; o >>= 1) v += __shfl_xor(v, o);
  if (t == 0) out[0] = 58.8120661251f - v / 8192.0f;  // 32*log(2*pi) - mean(lse)
}

extern "C" void kernel_launch(void* const* d_in, const int* in_sizes, int n_in,
                              void* d_out, int out_size, void* d_ws, size_t ws_size,
                              hipStream_t stream) {
  const float* x     = (const float*)d_in[0];
  const float* means = (const float*)d_in[1];
  const float* diag  = (const float*)d_in[2];
  const float* tri   = (const float*)d_in[3];
  const float* weigh = (const float*)d_in[4];

  char* ws = (char*)d_ws;
  uint16_t* Gf  = (uint16_t*)ws;
  float* ck     = (float*)(ws + OFF_CK);
  float* bpart  = (float*)(ws + OFF_BPART);
  float* val2   = (float*)(ws + OFF_VAL);

  p1_prep<<<dim3(256), dim3(256), 0, stream>>>(means, diag, tri, weigh, Gf, ck);
  k2_gemm<<<dim3(64, 4), dim3(256), 0, stream>>>(x, Gf, ck, val2);
  k3_lse<<<dim3(32), dim3(256), 0, stream>>>(val2, bpart);
  k4_final<<<dim3(1), dim3(64), 0, stream>>>(bpart, (float*)d_out);
}